// Round 19
// baseline (518.067 us; speedup 1.0000x reference)
//
#include <hip/hip_runtime.h>
#include <math.h>

#define T_DIM 8192
#define E_DIM 64
#define B_DIM 16
#define K_DIM 2048
#define N_PTS (B_DIM * T_DIM)      // 131072 points
#define N_ELEM (N_PTS * E_DIM)     // 8388608 elements
#define NBLK (N_PTS / 128)         // 1024 blocks

typedef __attribute__((ext_vector_type(8))) short short8;
typedef __attribute__((ext_vector_type(4))) float f32x4;

// ws layout (bytes):
//   [0, 16K)        : float4 red[1024]      per-block partials {fit, xsum, xn2, 0}
//   [32K, 40K)      : float cn2b[2048]      ||c||^2 + 256  (R3-exact)
//   [64K+2M, +512K) : swizzled bf16 hi/lo of codebook (UNSCALED, R3-exact)
#define WS_RED   0
#define WS_CN2   32768
#define WS_SWZ   (65536 + (size_t)2 * N_PTS * 8)

// LDS xs bank-swizzle: permute word index within a row (bits 2-4 only, so
// float4 stays 16B-aligned). Pure storage permutation - values untouched.
#define XSWZ(pt) ((((pt) >> 3) & 7) << 2)

__device__ __forceinline__ unsigned short f2bf_rne(float v) {
    unsigned int u = __float_as_uint(v);
    return (unsigned short)((u + 0x7FFFu + ((u >> 16) & 1u)) >> 16);
}

// async global->LDS 16B copy (no VGPR round-trip); bit-exact data movement
__device__ __forceinline__ void gload_lds16(const void* g, void* l) {
    __builtin_amdgcn_global_load_lds(
        (const __attribute__((address_space(1))) void*)g,
        (__attribute__((address_space(3))) void*)l,
        16, 0, 0);
}

// Combined prep: swizzled codebook (R3-exact) + cn2b (R3-exact).
// Swizzle: for cw-tile c16, frag (hl, es) is 64 lanes x 16B:
// lane l <-> cw = c16*16 + (l&15), e = es*32 + (l>>4)*8 .. +8
__global__ void prep_all(const float* __restrict__ cb,
                         float* __restrict__ cn2b,
                         unsigned short* __restrict__ swz) {
    int tid = blockIdx.x * 256 + threadIdx.x;   // 32768 threads
    int l   = tid & 63;
    int es  = (tid >> 6) & 1;
    int hl  = (tid >> 7) & 1;
    int c16 = tid >> 8;
    int cw  = c16 * 16 + (l & 15);
    int e0  = es * 32 + ((l >> 4) * 8);
    const float* src = cb + (size_t)cw * E_DIM + e0;
    short8 v;
#pragma unroll
    for (int j = 0; j < 8; ++j) {
        float f = src[j];
        unsigned short h = f2bf_rne(f);
        if (hl == 0) {
            v[j] = (short)h;
        } else {
            float hf = __uint_as_float(((unsigned int)h) << 16);
            v[j] = (short)f2bf_rne(f - hf);
        }
    }
    *(short8*)(swz + (size_t)c16 * 2048 + hl * 1024 + es * 512 + l * 8) = v;

    if (tid < K_DIM) {
        const float4* row = (const float4*)(cb + (size_t)tid * E_DIM);
        float s = 0.f;
#pragma unroll
        for (int j = 0; j < E_DIM / 4; ++j) {
            float4 c = row[j];
            s = fmaf(c.x, c.x, s);
            s = fmaf(c.y, c.y, s);
            s = fmaf(c.z, c.z, s);
            s = fmaf(c.w, c.w, s);
        }
        cn2b[tid] = s + 256.f;
    }
}

__device__ __forceinline__ void comp_step(
    const short8 (&Ah)[2][2], const short8 (&Al)[2][2],
    const short8 (&Bh)[2][2], const short8 (&Bl)[2][2],
    const float (&C2)[2], int s,
    unsigned int (&b1)[8], unsigned int (&b2)[8])
{
    const f32x4 zero = {0.f, 0.f, 0.f, 0.f};
#pragma unroll
    for (int rf = 0; rf < 2; ++rf) {
#pragma unroll
        for (int cf = 0; cf < 2; ++cf) {
            f32x4 acc;
            acc = __builtin_amdgcn_mfma_f32_16x16x32_bf16(Ah[rf][0], Bh[cf][0], zero, 0, 0, 0);
            acc = __builtin_amdgcn_mfma_f32_16x16x32_bf16(Ah[rf][1], Bh[cf][1], acc,  0, 0, 0);
            acc = __builtin_amdgcn_mfma_f32_16x16x32_bf16(Ah[rf][0], Bl[cf][0], acc,  0, 0, 0);
            acc = __builtin_amdgcn_mfma_f32_16x16x32_bf16(Ah[rf][1], Bl[cf][1], acc,  0, 0, 0);
            acc = __builtin_amdgcn_mfma_f32_16x16x32_bf16(Al[rf][0], Bh[cf][0], acc,  0, 0, 0);
            acc = __builtin_amdgcn_mfma_f32_16x16x32_bf16(Al[rf][1], Bh[cf][1], acc,  0, 0, 0);
            unsigned int orv = ((unsigned int)s << 1) | (unsigned int)cf;
#pragma unroll
            for (int r = 0; r < 4; ++r) {
                float d = fmaf(-2.f, acc[r], C2[cf]);   // >0 by +256 bias (R3-exact)
                unsigned int p = (__float_as_uint(d) & 0xFFFFFFC0u) | orv;
                int slot = rf * 4 + r;
                unsigned int t1 = b1[slot];
                unsigned int bb = b2[slot];
                // med3(t1, bb, p) == min(bb, max(t1, p)) given t1 <= bb invariant
                asm("v_med3_u32 %0, %1, %0, %2" : "+v"(bb) : "v"(t1), "v"(p));
                b2[slot] = bb;
                b1[slot] = min(t1, p);
            }
        }
    }
}

// 8-wave staging: wave w stages HALF of c16-tile (w>>1), half (w&1): 2KB/wave
__device__ __forceinline__ void stage_tile8(
    const short8* __restrict__ swz8, short8 (*buf)[256], int s, int w, int l)
{
    const int tw = w >> 1;
    const int h  = w & 1;
    const size_t gb = (size_t)(s * 4 + tw) * 256 + h * 128;
#pragma unroll
    for (int i = 0; i < 2; ++i)
        gload_lds16(&swz8[gb + i * 64 + l], &buf[tw][h * 128 + i * 64 + l]);
}

__global__ __launch_bounds__(512, 8) void vq_fused(
    const float* __restrict__ x, const unsigned short* __restrict__ swz,
    const float* __restrict__ cn2b, const float* __restrict__ cbf,
    float* __restrict__ out, float4* __restrict__ red)
{
    // phase-1: bstage[2][4][256] (32K) + cn2s[2048] (8K) = 40K
    // phase-2 (after K-loop): xs[128][68] (34.8K) + cand[128][4] (2K) +
    //                         sred[8][3] (96B @ +36864, overlays dead cn2s)
    // NO other __shared__ objects -> static LDS exactly 40960
    // 40960 * 4 blocks = exactly 160 KiB/CU -> 4 blocks/CU
    __shared__ __align__(16) char smem[40960];
    short8 (*bstage)[4][256] = (short8 (*)[4][256])smem;
    float* cn2s              = (float*)(smem + 32768);
    float (*xs)[68]          = (float (*)[68])smem;
    unsigned (*cand)[4]      = (unsigned (*)[4])(smem + 34816);
    float (*sred)[3]         = (float (*)[3])(smem + 36864);

    const int l  = threadIdx.x & 63;
    const int w  = threadIdx.x >> 6;   // 0..7
    const int wr = w >> 1;             // row-wave: 0..3 (32 points each)
    const int wc = w & 1;              // col-wave: half of codebook
    const int lm = l & 15;
    const int lg = l >> 4;
    const int n0 = blockIdx.x * 128 + wr * 32;

    // ---- A fragments: convert x to bf16 hi/lo (R3-exact conversion) ----
    short8 Ah[2][2], Al[2][2];
#pragma unroll
    for (int rf = 0; rf < 2; ++rf) {
        int n  = n0 + rf * 16 + lm;
        int bb = n >> 13;
        int tt = n & (T_DIM - 1);
#pragma unroll
        for (int es = 0; es < 2; ++es) {
            int e0 = es * 32 + lg * 8;
            const float* xp = x + ((size_t)bb * E_DIM + e0) * T_DIM + tt;
#pragma unroll
            for (int j = 0; j < 8; ++j) {
                float v = xp[(size_t)j * T_DIM];
                unsigned short h = f2bf_rne(v);
                float hf = __uint_as_float(((unsigned int)h) << 16);
                Ah[rf][es][j] = (short)h;
                Al[rf][es][j] = (short)f2bf_rne(v - hf);
            }
        }
    }

    // ---- cn2b -> LDS once (bit-exact f32 copy; 512 threads x float4 = 8KB) ----
    ((float4*)cn2s)[threadIdx.x] = ((const float4*)cn2b)[threadIdx.x];

    unsigned int b1[8], b2[8];
#pragma unroll
    for (int i = 0; i < 8; ++i) { b1[i] = 0xFFFFFFFFu; b2[i] = 0xFFFFFFFFu; }

    const short8* swz8 = (const short8*)swz;

    // ---- prologue: stage tile 0; drain (also covers cn2s ds_writes) ----
    stage_tile8(swz8, bstage[0], 0, w, l);
    __syncthreads();

    // ---- K loop: R12-exact schedule (2-buffer, 1 barrier/step) ----
    for (int s = 0; s < 32; ++s) {
        const int buf = s & 1;
        if (s < 31) {   // fire-and-forget async stage of next tile
            stage_tile8(swz8, bstage[buf ^ 1], s + 1, w, l);
        }
        short8 Bh[2][2], Bl[2][2];
        float c2[2];
#pragma unroll
        for (int cf = 0; cf < 2; ++cf) {
            const short8* tp = &bstage[buf][wc * 2 + cf][0];
            Bh[cf][0] = tp[l];
            Bh[cf][1] = tp[64 + l];
            Bl[cf][0] = tp[128 + l];
            Bl[cf][1] = tp[192 + l];
            c2[cf] = cn2s[s * 64 + wc * 32 + cf * 16 + lm];
        }
        comp_step(Ah, Al, Bh, Bl, c2, s, b1, b2);   // R3-exact math
        __syncthreads();   // drains staging vmcnt + orders dbuf swap
    }

    // ---- cross-lane merge within 16-lane groups (R3-exact); defer writes ----
    unsigned my1 = 0, my2 = 0;
    int myn = -1;
#pragma unroll
    for (int slot = 0; slot < 8; ++slot) {
        unsigned int p1 = b1[slot];
        unsigned int p2 = b2[slot];
        unsigned int d1 = p1 & 0xFFFFFFC0u;
        unsigned int d2 = p2 & 0xFFFFFFC0u;
        unsigned int scf1 = p1 & 63u, scf2 = p2 & 63u;
        unsigned int cw1 = ((scf1 >> 1) << 6) | ((unsigned)wc << 5) | ((scf1 & 1u) << 4) | (unsigned)lm;
        unsigned int cw2 = ((scf2 >> 1) << 6) | ((unsigned)wc << 5) | ((scf2 & 1u) << 4) | (unsigned)lm;
#pragma unroll
        for (int off = 1; off < 16; off <<= 1) {
            unsigned int od1 = (unsigned int)__shfl_xor((int)d1, off, 16);
            unsigned int oc1 = (unsigned int)__shfl_xor((int)cw1, off, 16);
            unsigned int od2 = (unsigned int)__shfl_xor((int)d2, off, 16);
            unsigned int oc2 = (unsigned int)__shfl_xor((int)cw2, off, 16);
            bool o1lt = (od1 < d1) || (od1 == d1 && oc1 < cw1);
            unsigned int m1d = o1lt ? od1 : d1,  m1c = o1lt ? oc1 : cw1;
            unsigned int x1d = o1lt ? d1  : od1, x1c = o1lt ? cw1 : oc1;  // max of firsts
            bool o2lt = (od2 < d2) || (od2 == d2 && oc2 < cw2);
            unsigned int m2d = o2lt ? od2 : d2,  m2c = o2lt ? oc2 : cw2;  // min of seconds
            bool xlt = (x1d < m2d) || (x1d == m2d && x1c < m2c);
            d1 = m1d; cw1 = m1c;
            d2 = xlt ? x1d : m2d;
            cw2 = xlt ? x1c : m2c;
        }
        if (lm == slot) {
            int rf = slot >> 2, r = slot & 3;
            my1 = cw1; my2 = cw2;
            myn = wr * 32 + rf * 16 + lg * 4 + r;   // 0..127 block-local point
        }
    }

    // ---- phase 2: bstage/cn2s dead; write cand + stage x into xs ----
    __syncthreads();   // all waves done reading bstage/cn2s
    if (myn >= 0) {
        cand[myn][wc * 2 + 0] = my1;
        cand[myn][wc * 2 + 1] = my2;
    }
    const int p0 = blockIdx.x * 128;
    const int b  = p0 >> 13;
    const int t0 = p0 & (T_DIM - 1);
    {
        const int tt = (threadIdx.x & 31) * 4;
        const int er = threadIdx.x >> 5;      // 0..15
        const float* xb = x + (size_t)b * E_DIM * T_DIM + t0;
#pragma unroll
        for (int pass = 0; pass < 4; ++pass) {
            int e = pass * 16 + er;           // e < 64 always
            float4 v = *(const float4*)(xb + (size_t)e * T_DIM + tt);
            xs[tt + 0][e ^ XSWZ(tt + 0)] = v.x;
            xs[tt + 1][e ^ XSWZ(tt + 1)] = v.y;
            xs[tt + 2][e ^ XSWZ(tt + 2)] = v.z;
            xs[tt + 3][e ^ XSWZ(tt + 3)] = v.w;
        }
    }
    __syncthreads();

    // ---- refine: 4 lanes/point (R13-finish arithmetic verbatim) ----
    const int pidx = w * 16 + lm;   // 0..127
    const int t    = t0 + pidx;
    const int sw   = XSWZ(pidx);
    int Ic = (int)cand[pidx][lg];

    const float4* rc = (const float4*)(cbf + (size_t)Ic * E_DIM);
    float ec = 0.f;
#pragma unroll
    for (int j = 0; j < E_DIM / 4; ++j) {
        float4 c  = rc[j];
        float4 xv = *(const float4*)&xs[pidx][(4 * j) ^ sw];
        float u;
        u = xv.x - c.x; ec = fmaf(u, u, ec);
        u = xv.y - c.y; ec = fmaf(u, u, ec);
        u = xv.z - c.z; ec = fmaf(u, u, ec);
        u = xv.w - c.w; ec = fmaf(u, u, ec);
    }

    float el = ec; int il = Ic;
#pragma unroll
    for (int off = 16; off <= 32; off <<= 1) {
        float oe = __shfl_xor(el, off);
        int   oi = __shfl_xor(il, off);
        if ((oe < el) || (oe == el && oi < il)) { el = oe; il = oi; }
    }

    int e0 = lg * 16;
    const float4* rw = (const float4*)(cbf + (size_t)il * E_DIM + e0);
    float* op = out + ((size_t)b * E_DIM + e0) * T_DIM + t;
    float xsum = 0.f, xn2 = 0.f;
#pragma unroll
    for (int j = 0; j < 4; ++j) {
        float4 c  = rw[j];
        float4 xv = *(const float4*)&xs[pidx][(e0 + 4 * j) ^ sw];
        op[(size_t)(4 * j + 0) * T_DIM] = c.x;
        op[(size_t)(4 * j + 1) * T_DIM] = c.y;
        op[(size_t)(4 * j + 2) * T_DIM] = c.z;
        op[(size_t)(4 * j + 3) * T_DIM] = c.w;
        xsum += xv.x + xv.y + xv.z + xv.w;
        xn2 = fmaf(xv.x, xv.x, xn2);
        xn2 = fmaf(xv.y, xv.y, xn2);
        xn2 = fmaf(xv.z, xv.z, xn2);
        xn2 = fmaf(xv.w, xv.w, xn2);
    }

    float v1 = (lg == 0) ? el : 0.f;   // fit counted once per point
    float v2 = xsum, v3 = xn2;
#pragma unroll
    for (int off = 32; off > 0; off >>= 1) {
        v1 += __shfl_down(v1, off);
        v2 += __shfl_down(v2, off);
        v3 += __shfl_down(v3, off);
    }
    if (l == 0) {
        sred[w][0] = v1; sred[w][1] = v2; sred[w][2] = v3;
    }
    __syncthreads();
    if (threadIdx.x == 0) {
        float s1 = 0, s2 = 0, s3 = 0;
        for (int u = 0; u < 8; ++u) {
            s1 += sred[u][0]; s2 += sred[u][1]; s3 += sred[u][2];
        }
        red[blockIdx.x] = make_float4(s1, s2, s3, 0.f);
    }
}

__global__ __launch_bounds__(64) void finalize_kernel(
    const float4* __restrict__ red, float* __restrict__ out_scalars)
{
    int lane = threadIdx.x;
    double s1 = 0, s2 = 0, s3 = 0;
    for (int i = lane; i < NBLK; i += 64) {   // 1024 partials
        float4 v = red[i];
        s1 += (double)v.x; s2 += (double)v.y; s3 += (double)v.z;
    }
#pragma unroll
    for (int off = 32; off > 0; off >>= 1) {
        s1 += __shfl_down(s1, off);
        s2 += __shfl_down(s2, off);
        s3 += __shfl_down(s3, off);
    }
    if (lane == 0) {
        out_scalars[0] = (float)(s1 / (double)N_ELEM);   // commit = sum(min d)/n_elem
        out_scalars[1] = (float)(s1 / (double)N_PTS);    // fit = mean(min d)
        double mean = s2 / (double)N_ELEM;
        double var  = s3 / (double)N_ELEM - mean * mean;
        out_scalars[2] = (float)sqrt(var > 0.0 ? var : 0.0);
    }
}

extern "C" void kernel_launch(void* const* d_in, const int* in_sizes, int n_in,
                              void* d_out, int out_size, void* d_ws, size_t ws_size,
                              hipStream_t stream) {
    const float* x  = (const float*)d_in[0];
    const float* cb = (const float*)d_in[1];
    float* out = (float*)d_out;
    float4* red = (float4*)((char*)d_ws + WS_RED);
    float* cn2b = (float*)((char*)d_ws + WS_CN2);
    unsigned short* swz = (unsigned short*)((char*)d_ws + WS_SWZ);

    prep_all<<<128, 256, 0, stream>>>(cb, cn2b, swz);
    vq_fused<<<NBLK, 512, 0, stream>>>(x, swz, cn2b, cb, out, red);
    finalize_kernel<<<1, 64, 0, stream>>>(red, out + N_ELEM);
}

// Round 20
// 135.558 us; speedup vs baseline: 3.8217x; 3.8217x over previous
//
#include <hip/hip_runtime.h>
#include <math.h>

#define T_DIM 8192
#define E_DIM 64
#define B_DIM 16
#define K_DIM 2048
#define N_PTS (B_DIM * T_DIM)      // 131072 points
#define N_ELEM (N_PTS * E_DIM)     // 8388608 elements
#define NBLK (N_PTS / 128)         // 1024 blocks

typedef __attribute__((ext_vector_type(8))) short short8;
typedef __attribute__((ext_vector_type(4))) float f32x4;

// ws layout (bytes):
//   [0, 16K)        : float4 red[1024]      per-block partials {fit, xsum, xn2, 0}
//   [32K, 40K)      : float cn2b[2048]      ||c||^2 + 256  (R3-exact)
//   [64K+2M, +512K) : swizzled bf16 hi/lo of codebook (UNSCALED, R3-exact)
#define WS_RED   0
#define WS_CN2   32768
#define WS_SWZ   (65536 + (size_t)2 * N_PTS * 8)

// LDS xs bank-swizzle: permute word index within a row (bits 2-4 only, so
// float4 stays 16B-aligned). Pure storage permutation - values untouched.
#define XSWZ(pt) ((((pt) >> 3) & 7) << 2)

__device__ __forceinline__ unsigned short f2bf_rne(float v) {
    unsigned int u = __float_as_uint(v);
    return (unsigned short)((u + 0x7FFFu + ((u >> 16) & 1u)) >> 16);
}

// async global->LDS 16B copy (no VGPR round-trip); bit-exact data movement
__device__ __forceinline__ void gload_lds16(const void* g, void* l) {
    __builtin_amdgcn_global_load_lds(
        (const __attribute__((address_space(1))) void*)g,
        (__attribute__((address_space(3))) void*)l,
        16, 0, 0);
}

// Combined prep: swizzled codebook (R3-exact) + cn2b (R3-exact).
// Swizzle: for cw-tile c16, frag (hl, es) is 64 lanes x 16B:
// lane l <-> cw = c16*16 + (l&15), e = es*32 + (l>>4)*8 .. +8
__global__ void prep_all(const float* __restrict__ cb,
                         float* __restrict__ cn2b,
                         unsigned short* __restrict__ swz) {
    int tid = blockIdx.x * 256 + threadIdx.x;   // 32768 threads
    int l   = tid & 63;
    int es  = (tid >> 6) & 1;
    int hl  = (tid >> 7) & 1;
    int c16 = tid >> 8;
    int cw  = c16 * 16 + (l & 15);
    int e0  = es * 32 + ((l >> 4) * 8);
    const float* src = cb + (size_t)cw * E_DIM + e0;
    short8 v;
#pragma unroll
    for (int j = 0; j < 8; ++j) {
        float f = src[j];
        unsigned short h = f2bf_rne(f);
        if (hl == 0) {
            v[j] = (short)h;
        } else {
            float hf = __uint_as_float(((unsigned int)h) << 16);
            v[j] = (short)f2bf_rne(f - hf);
        }
    }
    *(short8*)(swz + (size_t)c16 * 2048 + hl * 1024 + es * 512 + l * 8) = v;

    if (tid < K_DIM) {
        const float4* row = (const float4*)(cb + (size_t)tid * E_DIM);
        float s = 0.f;
#pragma unroll
        for (int j = 0; j < E_DIM / 4; ++j) {
            float4 c = row[j];
            s = fmaf(c.x, c.x, s);
            s = fmaf(c.y, c.y, s);
            s = fmaf(c.z, c.z, s);
            s = fmaf(c.w, c.w, s);
        }
        cn2b[tid] = s + 256.f;
    }
}

__device__ __forceinline__ void comp_step(
    const short8 (&Ah)[2][2], const short8 (&Al)[2][2],
    const short8 (&Bh)[2][2], const short8 (&Bl)[2][2],
    const float (&C2)[2], int s,
    unsigned int (&b1)[8], unsigned int (&b2)[8])
{
    const f32x4 zero = {0.f, 0.f, 0.f, 0.f};
#pragma unroll
    for (int rf = 0; rf < 2; ++rf) {
#pragma unroll
        for (int cf = 0; cf < 2; ++cf) {
            f32x4 acc;
            acc = __builtin_amdgcn_mfma_f32_16x16x32_bf16(Ah[rf][0], Bh[cf][0], zero, 0, 0, 0);
            acc = __builtin_amdgcn_mfma_f32_16x16x32_bf16(Ah[rf][1], Bh[cf][1], acc,  0, 0, 0);
            acc = __builtin_amdgcn_mfma_f32_16x16x32_bf16(Ah[rf][0], Bl[cf][0], acc,  0, 0, 0);
            acc = __builtin_amdgcn_mfma_f32_16x16x32_bf16(Ah[rf][1], Bl[cf][1], acc,  0, 0, 0);
            acc = __builtin_amdgcn_mfma_f32_16x16x32_bf16(Al[rf][0], Bh[cf][0], acc,  0, 0, 0);
            acc = __builtin_amdgcn_mfma_f32_16x16x32_bf16(Al[rf][1], Bh[cf][1], acc,  0, 0, 0);
            unsigned int orv = ((unsigned int)s << 1) | (unsigned int)cf;
#pragma unroll
            for (int r = 0; r < 4; ++r) {
                float d = fmaf(-2.f, acc[r], C2[cf]);   // >0 by +256 bias (R3-exact)
                unsigned int p = (__float_as_uint(d) & 0xFFFFFFC0u) | orv;
                int slot = rf * 4 + r;
                unsigned int t1 = b1[slot];
                unsigned int bb = b2[slot];
                // med3(t1, bb, p) == min(bb, max(t1, p)) given t1 <= bb invariant
                asm("v_med3_u32 %0, %1, %0, %2" : "+v"(bb) : "v"(t1), "v"(p));
                b2[slot] = bb;
                b1[slot] = min(t1, p);
            }
        }
    }
}

// 8-wave staging: wave w stages HALF of c16-tile (w>>1), half (w&1): 2KB/wave
__device__ __forceinline__ void stage_tile8(
    const short8* __restrict__ swz8, short8 (*buf)[256], int s, int w, int l)
{
    const int tw = w >> 1;
    const int h  = w & 1;
    const size_t gb = (size_t)(s * 4 + tw) * 256 + h * 128;
#pragma unroll
    for (int i = 0; i < 2; ++i)
        gload_lds16(&swz8[gb + i * 64 + l], &buf[tw][h * 128 + i * 64 + l]);
}

__global__ __launch_bounds__(512) void vq_fused(
    const float* __restrict__ x, const unsigned short* __restrict__ swz,
    const float* __restrict__ cn2b, const float* __restrict__ cbf,
    float* __restrict__ out, float4* __restrict__ red)
{
    // phase-1: bstage[2][4][256] (32K) + cn2s[2048] (8K) = 40K
    // phase-2 (after K-loop): xs[128][68] (34.8K) + cand[128][4] (2K) +
    //                         sred[8][3] (96B @ +36864, overlays dead cn2s)
    // NO other __shared__ objects -> static LDS exactly 40960
    __shared__ __align__(16) char smem[40960];
    short8 (*bstage)[4][256] = (short8 (*)[4][256])smem;
    float* cn2s              = (float*)(smem + 32768);
    float (*xs)[68]          = (float (*)[68])smem;
    unsigned (*cand)[4]      = (unsigned (*)[4])(smem + 34816);
    float (*sred)[3]         = (float (*)[3])(smem + 36864);

    const int l  = threadIdx.x & 63;
    const int w  = threadIdx.x >> 6;   // 0..7
    const int wr = w >> 1;             // row-wave: 0..3 (32 points each)
    const int wc = w & 1;              // col-wave: half of codebook
    const int lm = l & 15;
    const int lg = l >> 4;
    const int n0 = blockIdx.x * 128 + wr * 32;

    // ---- A fragments: convert x to bf16 hi/lo (R3-exact conversion) ----
    short8 Ah[2][2], Al[2][2];
#pragma unroll
    for (int rf = 0; rf < 2; ++rf) {
        int n  = n0 + rf * 16 + lm;
        int bb = n >> 13;
        int tt = n & (T_DIM - 1);
#pragma unroll
        for (int es = 0; es < 2; ++es) {
            int e0 = es * 32 + lg * 8;
            const float* xp = x + ((size_t)bb * E_DIM + e0) * T_DIM + tt;
#pragma unroll
            for (int j = 0; j < 8; ++j) {
                float v = xp[(size_t)j * T_DIM];
                unsigned short h = f2bf_rne(v);
                float hf = __uint_as_float(((unsigned int)h) << 16);
                Ah[rf][es][j] = (short)h;
                Al[rf][es][j] = (short)f2bf_rne(v - hf);
            }
        }
    }

    // ---- cn2b -> LDS once (bit-exact f32 copy; 512 threads x float4 = 8KB) ----
    ((float4*)cn2s)[threadIdx.x] = ((const float4*)cn2b)[threadIdx.x];

    unsigned int b1[8], b2[8];
#pragma unroll
    for (int i = 0; i < 8; ++i) { b1[i] = 0xFFFFFFFFu; b2[i] = 0xFFFFFFFFu; }

    const short8* swz8 = (const short8*)swz;

    // ---- prologue: stage tile 0; drain (also covers cn2s ds_writes) ----
    stage_tile8(swz8, bstage[0], 0, w, l);
    __syncthreads();

    // ---- K loop: R12-exact schedule (2-buffer, 1 barrier/step) ----
    for (int s = 0; s < 32; ++s) {
        const int buf = s & 1;
        if (s < 31) {   // fire-and-forget async stage of next tile
            stage_tile8(swz8, bstage[buf ^ 1], s + 1, w, l);
        }
        short8 Bh[2][2], Bl[2][2];
        float c2[2];
#pragma unroll
        for (int cf = 0; cf < 2; ++cf) {
            const short8* tp = &bstage[buf][wc * 2 + cf][0];
            Bh[cf][0] = tp[l];
            Bh[cf][1] = tp[64 + l];
            Bl[cf][0] = tp[128 + l];
            Bl[cf][1] = tp[192 + l];
            c2[cf] = cn2s[s * 64 + wc * 32 + cf * 16 + lm];
        }
        comp_step(Ah, Al, Bh, Bl, c2, s, b1, b2);   // R3-exact math
        __syncthreads();   // drains staging vmcnt + orders dbuf swap
    }

    // ---- cross-lane merge within 16-lane groups (R3-exact); defer writes ----
    unsigned my1 = 0, my2 = 0;
    int myn = -1;
#pragma unroll
    for (int slot = 0; slot < 8; ++slot) {
        unsigned int p1 = b1[slot];
        unsigned int p2 = b2[slot];
        unsigned int d1 = p1 & 0xFFFFFFC0u;
        unsigned int d2 = p2 & 0xFFFFFFC0u;
        unsigned int scf1 = p1 & 63u, scf2 = p2 & 63u;
        unsigned int cw1 = ((scf1 >> 1) << 6) | ((unsigned)wc << 5) | ((scf1 & 1u) << 4) | (unsigned)lm;
        unsigned int cw2 = ((scf2 >> 1) << 6) | ((unsigned)wc << 5) | ((scf2 & 1u) << 4) | (unsigned)lm;
#pragma unroll
        for (int off = 1; off < 16; off <<= 1) {
            unsigned int od1 = (unsigned int)__shfl_xor((int)d1, off, 16);
            unsigned int oc1 = (unsigned int)__shfl_xor((int)cw1, off, 16);
            unsigned int od2 = (unsigned int)__shfl_xor((int)d2, off, 16);
            unsigned int oc2 = (unsigned int)__shfl_xor((int)cw2, off, 16);
            bool o1lt = (od1 < d1) || (od1 == d1 && oc1 < cw1);
            unsigned int m1d = o1lt ? od1 : d1,  m1c = o1lt ? oc1 : cw1;
            unsigned int x1d = o1lt ? d1  : od1, x1c = o1lt ? cw1 : oc1;  // max of firsts
            bool o2lt = (od2 < d2) || (od2 == d2 && oc2 < cw2);
            unsigned int m2d = o2lt ? od2 : d2,  m2c = o2lt ? oc2 : cw2;  // min of seconds
            bool xlt = (x1d < m2d) || (x1d == m2d && x1c < m2c);
            d1 = m1d; cw1 = m1c;
            d2 = xlt ? x1d : m2d;
            cw2 = xlt ? x1c : m2c;
        }
        if (lm == slot) {
            int rf = slot >> 2, r = slot & 3;
            my1 = cw1; my2 = cw2;
            myn = wr * 32 + rf * 16 + lg * 4 + r;   // 0..127 block-local point
        }
    }

    // ---- phase 2: bstage/cn2s dead; write cand + stage x into xs ----
    __syncthreads();   // all waves done reading bstage/cn2s
    if (myn >= 0) {
        cand[myn][wc * 2 + 0] = my1;
        cand[myn][wc * 2 + 1] = my2;
    }
    const int p0 = blockIdx.x * 128;
    const int b  = p0 >> 13;
    const int t0 = p0 & (T_DIM - 1);
    {
        const int tt = (threadIdx.x & 31) * 4;
        const int er = threadIdx.x >> 5;      // 0..15
        const float* xb = x + (size_t)b * E_DIM * T_DIM + t0;
#pragma unroll
        for (int pass = 0; pass < 4; ++pass) {
            int e = pass * 16 + er;           // e < 64 always
            float4 v = *(const float4*)(xb + (size_t)e * T_DIM + tt);
            xs[tt + 0][e ^ XSWZ(tt + 0)] = v.x;
            xs[tt + 1][e ^ XSWZ(tt + 1)] = v.y;
            xs[tt + 2][e ^ XSWZ(tt + 2)] = v.z;
            xs[tt + 3][e ^ XSWZ(tt + 3)] = v.w;
        }
    }
    __syncthreads();

    // ---- refine: 4 lanes/point (R13-finish arithmetic verbatim) ----
    const int pidx = w * 16 + lm;   // 0..127
    const int t    = t0 + pidx;
    const int sw   = XSWZ(pidx);
    int Ic = (int)cand[pidx][lg];

    const float4* rc = (const float4*)(cbf + (size_t)Ic * E_DIM);
    float ec = 0.f;
#pragma unroll
    for (int j = 0; j < E_DIM / 4; ++j) {
        float4 c  = rc[j];
        float4 xv = *(const float4*)&xs[pidx][(4 * j) ^ sw];
        float u;
        u = xv.x - c.x; ec = fmaf(u, u, ec);
        u = xv.y - c.y; ec = fmaf(u, u, ec);
        u = xv.z - c.z; ec = fmaf(u, u, ec);
        u = xv.w - c.w; ec = fmaf(u, u, ec);
    }

    float el = ec; int il = Ic;
#pragma unroll
    for (int off = 16; off <= 32; off <<= 1) {
        float oe = __shfl_xor(el, off);
        int   oi = __shfl_xor(il, off);
        if ((oe < el) || (oe == el && oi < il)) { el = oe; il = oi; }
    }

    int e0 = lg * 16;
    const float4* rw = (const float4*)(cbf + (size_t)il * E_DIM + e0);
    float* op = out + ((size_t)b * E_DIM + e0) * T_DIM + t;
    float xsum = 0.f, xn2 = 0.f;
#pragma unroll
    for (int j = 0; j < 4; ++j) {
        float4 c  = rw[j];
        float4 xv = *(const float4*)&xs[pidx][(e0 + 4 * j) ^ sw];
        op[(size_t)(4 * j + 0) * T_DIM] = c.x;
        op[(size_t)(4 * j + 1) * T_DIM] = c.y;
        op[(size_t)(4 * j + 2) * T_DIM] = c.z;
        op[(size_t)(4 * j + 3) * T_DIM] = c.w;
        xsum += xv.x + xv.y + xv.z + xv.w;
        xn2 = fmaf(xv.x, xv.x, xn2);
        xn2 = fmaf(xv.y, xv.y, xn2);
        xn2 = fmaf(xv.z, xv.z, xn2);
        xn2 = fmaf(xv.w, xv.w, xn2);
    }

    float v1 = (lg == 0) ? el : 0.f;   // fit counted once per point
    float v2 = xsum, v3 = xn2;
#pragma unroll
    for (int off = 32; off > 0; off >>= 1) {
        v1 += __shfl_down(v1, off);
        v2 += __shfl_down(v2, off);
        v3 += __shfl_down(v3, off);
    }
    if (l == 0) {
        sred[w][0] = v1; sred[w][1] = v2; sred[w][2] = v3;
    }
    __syncthreads();
    if (threadIdx.x == 0) {
        float s1 = 0, s2 = 0, s3 = 0;
        for (int u = 0; u < 8; ++u) {
            s1 += sred[u][0]; s2 += sred[u][1]; s3 += sred[u][2];
        }
        red[blockIdx.x] = make_float4(s1, s2, s3, 0.f);
    }
}

__global__ __launch_bounds__(64) void finalize_kernel(
    const float4* __restrict__ red, float* __restrict__ out_scalars)
{
    int lane = threadIdx.x;
    double s1 = 0, s2 = 0, s3 = 0;
    for (int i = lane; i < NBLK; i += 64) {   // 1024 partials
        float4 v = red[i];
        s1 += (double)v.x; s2 += (double)v.y; s3 += (double)v.z;
    }
#pragma unroll
    for (int off = 32; off > 0; off >>= 1) {
        s1 += __shfl_down(s1, off);
        s2 += __shfl_down(s2, off);
        s3 += __shfl_down(s3, off);
    }
    if (lane == 0) {
        out_scalars[0] = (float)(s1 / (double)N_ELEM);   // commit = sum(min d)/n_elem
        out_scalars[1] = (float)(s1 / (double)N_PTS);    // fit = mean(min d)
        double mean = s2 / (double)N_ELEM;
        double var  = s3 / (double)N_ELEM - mean * mean;
        out_scalars[2] = (float)sqrt(var > 0.0 ? var : 0.0);
    }
}

extern "C" void kernel_launch(void* const* d_in, const int* in_sizes, int n_in,
                              void* d_out, int out_size, void* d_ws, size_t ws_size,
                              hipStream_t stream) {
    const float* x  = (const float*)d_in[0];
    const float* cb = (const float*)d_in[1];
    float* out = (float*)d_out;
    float4* red = (float4*)((char*)d_ws + WS_RED);
    float* cn2b = (float*)((char*)d_ws + WS_CN2);
    unsigned short* swz = (unsigned short*)((char*)d_ws + WS_SWZ);

    prep_all<<<128, 256, 0, stream>>>(cb, cn2b, swz);
    vq_fused<<<NBLK, 512, 0, stream>>>(x, swz, cn2b, cb, out, red);
    finalize_kernel<<<1, 64, 0, stream>>>(red, out + N_ELEM);
}